// Round 3
// baseline (206.395 us; speedup 1.0000x reference)
//
#include <hip/hip_runtime.h>

// LIF layer fused step, f32.
// Inputs (setup_inputs order):
//   d_in[0] input_spikes [8192]      f32
//   d_in[1] voltages     [1, 8192]   f32
//   d_in[2] synapses     [8192,8192] f32
//   d_in[3] weights      [8192,8192] f32
// Outputs (return order, concatenated flat in d_out, f32):
//   [0 .. 8192)            spikes (bool -> 0.0/1.0)
//   [8192 .. 16384)        v_new
//   [16384 .. 16384+64M)   syn

#define V_DECAY 0.99004983374916811f   // exp(-1/100)
#define S_DECAY 0.98019867330675525f   // exp(-1/50)
#define THRESH  1.0f

constexpr int N_IN  = 8192;
constexpr int N_OUT = 8192;
constexpr int COLS_PER_BLOCK = 1024;               // 256 threads x 4 floats
constexpr int COL_TILES = N_OUT / COLS_PER_BLOCK;  // 8

// Native clang vector type: __builtin_nontemporal_store requires a vector of
// float, not HIP's struct-based float4.
typedef float f32x4 __attribute__((ext_vector_type(4)));

// Kernel 1: syn = synapses*S_DECAY + weights*spike_row; write syn (non-temporal,
// never re-read); emit per-(row-chunk, column) partial sums into d_ws.
__global__ __launch_bounds__(256) void lif_syn_kernel(
    const float* __restrict__ input_spikes,
    const float* __restrict__ synapses,
    const float* __restrict__ weights,
    float* __restrict__ syn_out,
    float* __restrict__ partials,       // [rowChunks][N_OUT]
    int rowsPerChunk)
{
    const int ct   = blockIdx.x % COL_TILES;
    const int rc   = blockIdx.x / COL_TILES;
    const int col  = ct * COLS_PER_BLOCK + threadIdx.x * 4;
    const int row0 = rc * rowsPerChunk;

    f32x4 acc = (f32x4)(0.f);
    #pragma unroll 4
    for (int r = 0; r < rowsPerChunk; ++r) {
        const int row    = row0 + r;
        const size_t idx = (size_t)row * N_OUT + col;
        const f32x4 s4 = *reinterpret_cast<const f32x4*>(synapses + idx);
        const f32x4 w4 = *reinterpret_cast<const f32x4*>(weights  + idx);
        const float sp = input_spikes[row];   // block-uniform, scalar-cached
        const f32x4 o  = s4 * S_DECAY + w4 * sp;
        // Streaming store: syn is write-once, keep it out of L2/L3 so the
        // 512 MB of inputs stay resident in Infinity Cache across replays.
        __builtin_nontemporal_store(o, reinterpret_cast<f32x4*>(syn_out + idx));
        acc += o;
    }
    __builtin_nontemporal_store(
        acc, reinterpret_cast<f32x4*>(partials + (size_t)rc * N_OUT + col));
}

// Kernel 2: reduce partials per column, compute spike + v_new.
__global__ __launch_bounds__(256) void lif_v_kernel(
    const float* __restrict__ voltages,
    const float* __restrict__ partials,
    float* __restrict__ out,            // out[0..N_OUT)=spikes, [N_OUT..2N)=v_new
    int rowChunks)
{
    const int c = blockIdx.x * blockDim.x + threadIdx.x;
    const float v     = voltages[c] * V_DECAY;
    const float spike = (v >= THRESH) ? 1.0f : 0.0f;
    float sum = 0.f;
    #pragma unroll 4
    for (int rc = 0; rc < rowChunks; ++rc)
        sum += partials[(size_t)rc * N_OUT + c];   // coalesced across threads
    out[c]          = spike;
    out[N_OUT + c]  = v + sum - spike * THRESH;
}

extern "C" void kernel_launch(void* const* d_in, const int* in_sizes, int n_in,
                              void* d_out, int out_size, void* d_ws, size_t ws_size,
                              hipStream_t stream) {
    const float* input_spikes = (const float*)d_in[0];
    const float* voltages     = (const float*)d_in[1];
    const float* synapses     = (const float*)d_in[2];
    const float* weights      = (const float*)d_in[3];

    float* out      = (float*)d_out;
    float* syn_out  = out + 2 * N_OUT;
    float* partials = (float*)d_ws;

    // Largest power-of-two row-chunk count whose partial buffer fits d_ws.
    // Prefer 512 chunks (16 rows/block -> 4096 blocks -> ~16 blocks/CU queued).
    int rowChunks = 512;
    while (rowChunks > 1 &&
           (size_t)rowChunks * N_OUT * sizeof(float) > ws_size)
        rowChunks >>= 1;
    const int rowsPerChunk = N_IN / rowChunks;

    lif_syn_kernel<<<dim3(COL_TILES * rowChunks), dim3(256), 0, stream>>>(
        input_spikes, synapses, weights, syn_out, partials, rowsPerChunk);

    lif_v_kernel<<<dim3(N_OUT / 256), dim3(256), 0, stream>>>(
        voltages, partials, out, rowChunks);
}